// Round 8
// baseline (811.588 us; speedup 1.0000x reference)
//
#include <hip/hip_runtime.h>
#include <cstdint>

#define T_TOK 1024
#define HID   2048
#define NEXP  64
#define TOPK  8
#define INTER 768

typedef __attribute__((ext_vector_type(8))) short short8;   // 8 x bf16
typedef __attribute__((ext_vector_type(4))) float f32x4;

__device__ __forceinline__ unsigned short f2bf(float f){
  unsigned u = __float_as_uint(f);
  u += 0x7FFFu + ((u >> 16) & 1u);   // RNE
  return (unsigned short)(u >> 16);
}

__device__ __forceinline__ unsigned cvtpk(float lo, float hi){
  unsigned r;
  asm("v_cvt_pk_bf16_f32 %0, %1, %2" : "=v"(r) : "v"(lo), "v"(hi));
  return r;
}

// ---------------- kernel 1: x (fp32) -> bf16 once per launch ----------------
__global__ void k_convert_x(const float* __restrict__ x, unsigned short* __restrict__ xbf){
  int gid = blockIdx.x * 256 + threadIdx.x;
  const float4* src = (const float4*)(x + (size_t)gid * 8);
  float4 a = src[0], b = src[1];
  uint4 p;
  p.x = f2bf(a.x) | ((unsigned)f2bf(a.y) << 16);
  p.y = f2bf(a.z) | ((unsigned)f2bf(a.w) << 16);
  p.z = f2bf(b.x) | ((unsigned)f2bf(b.y) << 16);
  p.w = f2bf(b.z) | ((unsigned)f2bf(b.w) << 16);
  *(uint4*)(xbf + (size_t)gid * 8) = p;
}

// ---------------- kernel 2: router (fp32-exact logits, top-8) ----------------
__global__ void k_router(const float* __restrict__ x, const float* __restrict__ gw,
                         int* __restrict__ top_idx, float* __restrict__ top_w){
  int t = blockIdx.x;
  int tid = threadIdx.x;
  __shared__ float  xs[HID];
  __shared__ double part[4][NEXP];
  for (int i = tid; i < HID; i += 256) xs[i] = x[(size_t)t * HID + i];
  __syncthreads();
  int e = tid & 63, q = tid >> 6;
  double acc = 0.0;
  const float* gp = gw + e;
  #pragma unroll 8
  for (int h = q * 512; h < q * 512 + 512; ++h)
    acc += (double)xs[h] * (double)gp[(size_t)h * NEXP];
  part[q][e] = acc;
  __syncthreads();
  if (tid < 64){
    float logit = (float)(part[0][e] + part[1][e] + part[2][e] + part[3][e]);
    float cur = logit;
    float vals[TOPK]; int idxs[TOPK];
    #pragma unroll
    for (int k = 0; k < TOPK; ++k){
      float m = cur; int mi = e;
      #pragma unroll
      for (int off = 32; off > 0; off >>= 1){
        float ov = __shfl_xor(m, off);
        int   oi = __shfl_xor(mi, off);
        if (ov > m || (ov == m && oi < mi)){ m = ov; mi = oi; }
      }
      vals[k] = m; idxs[k] = mi;
      if (e == mi) cur = -1e30f;
    }
    float mx = vals[0], s = 0.f, ev[TOPK];
    #pragma unroll
    for (int k = 0; k < TOPK; ++k){ ev[k] = expf(vals[k] - mx); s += ev[k]; }
    #pragma unroll
    for (int k = 0; k < TOPK; ++k)
      if (e == k){ top_idx[t * TOPK + k] = idxs[k]; top_w[t * TOPK + k] = ev[k] / s; }
  }
}

// ---------------- kernel 3: per-expert histogram + exclusive scan ----------------
__global__ void k_hist(const int* __restrict__ top_idx, int* __restrict__ offs){
  __shared__ int hist[NEXP];
  int tid = threadIdx.x;
  if (tid < NEXP) hist[tid] = 0;
  __syncthreads();
  for (int j = tid; j < T_TOK * TOPK; j += 256) atomicAdd(&hist[top_idx[j]], 1);
  __syncthreads();
  if (tid == 0){
    int run = 0;
    for (int e = 0; e < NEXP; ++e){ offs[e] = run; run += hist[e]; }
    offs[NEXP] = run;
  }
}

// ---------------- kernel 4: deterministic ordered compaction ----------------
__global__ void k_compact(const int* __restrict__ top_idx, const float* __restrict__ top_w,
                          const int* __restrict__ offs, int* __restrict__ list_t,
                          float* __restrict__ list_w, int* __restrict__ slot_of){
  int e = blockIdx.x, tid = threadIdx.x;
  __shared__ int sc[256];
  int j0 = tid * 32, cnt = 0;
  for (int jj = 0; jj < 32; ++jj) cnt += (top_idx[j0 + jj] == e);
  sc[tid] = cnt; __syncthreads();
  for (int d = 1; d < 256; d <<= 1){
    int v = (tid >= d) ? sc[tid - d] : 0;
    __syncthreads();
    sc[tid] += v;
    __syncthreads();
  }
  int pos = offs[e] + sc[tid] - cnt;
  for (int jj = 0; jj < 32; ++jj){
    int j = j0 + jj;
    if (top_idx[j] == e){
      list_t[pos]  = j >> 3;
      list_w[pos]  = top_w[j];
      slot_of[j]   = pos;
      ++pos;
    }
  }
}

// ---------------- kernel 5: gate/up GEMM + SwiGLU ----------------
// Wave-autonomous streaming GEMM: NO barriers / NO LDS staging in the K-loop.
// Block = 48 rows x 64 cols x {gate,up}; 4 waves: (pair = w>>1 -> 32-col slice,
// mat = w&1 -> gate or up). Per wave: 48 rows (3 frags) x 32 cols (2 col-pair frags).
// B: per-lane float2 (16 lanes x 8 B = 128-B lines fully consumed), 2-deep reg
// pipeline, cvt_pk to bf16 in-register. A: b128 from L2/L3-resident xbf.
// XCD swizzle: 4 row-groups of one (e,ib) adjacent in per-XCD dispatch -> L2 dedup.
// End-of-loop LDS exchange for SwiGLU (up waves -> gate waves), then act store.
__global__ __launch_bounds__(256) void k_gateup(
    const unsigned short* __restrict__ xbf, const float* __restrict__ wg,
    const float* __restrict__ wu, const int* __restrict__ offs,
    const int* __restrict__ list_t, const float* __restrict__ list_w,
    unsigned short* __restrict__ act){
  int bid = blockIdx.x;                 // 3072 = 768 pairs x 4 grps, XCD-swizzled
  int xcd = bid & 7, seq = bid >> 3;    // seq 0..383 per XCD
  int pair = (seq >> 2) * 8 + xcd;      // 0..767  (same pair -> 4 adjacent per-XCD slots)
  int grp  = seq & 3;
  int e = pair / 12, ib = pair % 12;
  int beg = offs[e], n_e = offs[e + 1] - beg;
  int tid = threadIdx.x, lane = tid & 63, w = tid >> 6;
  int cL = lane & 15, q = lane >> 4;
  int mat = w & 1, pi = w >> 1;
  int iw = ib * 64 + pi * 32;

  __shared__ float lsU[2][64][25];      // up-acc exchange (pad 25: conflict-free)

  const float* Wm = (mat ? wu : wg) + (size_t)e * HID * INTER;
  const float* bP = Wm + (size_t)(8 * q) * INTER + iw + 2 * cL;

#define GU_LA(T, A_) { _Pragma("unroll") for (int f = 0; f < 3; ++f) \
      A_[f] = *(const short8*)(aP[f] + (T) * 32); }
#define GU_LB(T, B_) { _Pragma("unroll") for (int j = 0; j < 8; ++j) \
      B_[j] = *(const float2*)(bP + (size_t)((T) * 32 + j) * INTER); }
#define GU_CP(A_, B_) { \
      union { unsigned u[4]; short8 s; } f0, f1; \
      _Pragma("unroll") for (int rI = 0; rI < 4; ++rI){ \
        f0.u[rI] = cvtpk(B_[2*rI].x, B_[2*rI+1].x); \
        f1.u[rI] = cvtpk(B_[2*rI].y, B_[2*rI+1].y); } \
      _Pragma("unroll") for (int f = 0; f < 3; ++f){ \
        acc[f][0] = __builtin_amdgcn_mfma_f32_16x16x32_bf16(A_[f], f0.s, acc[f][0], 0, 0, 0); \
        acc[f][1] = __builtin_amdgcn_mfma_f32_16x16x32_bf16(A_[f], f1.s, acc[f][1], 0, 0, 0); } }

  for (int r0 = grp * 48; r0 < n_e; r0 += 192){
    const unsigned short* aP[3];
    #pragma unroll
    for (int f = 0; f < 3; ++f){
      int r = r0 + f * 16 + cL;
      int tok = list_t[(r < n_e) ? (beg + r) : beg];
      aP[f] = xbf + (size_t)tok * HID + 8 * q;
    }
    short8 a0[3], a1[3];
    float2 b0[8], b1[8];
    f32x4 acc[3][2] = {};

    GU_LA(0, a0); GU_LB(0, b0);
    #pragma unroll 1
    for (int t = 0; t < 64; t += 2){
      GU_LA(t + 1, a1); GU_LB(t + 1, b1);   // in flight across the MFMA waits below
      GU_CP(a0, b0);
      if (t + 2 < 64){ GU_LA(t + 2, a0); GU_LB(t + 2, b0); }
      GU_CP(a1, b1);
    }

    // SwiGLU exchange: up waves publish, gate waves combine + store
    if (mat == 1){
      #pragma unroll
      for (int f = 0; f < 3; ++f)
        #pragma unroll
        for (int rr = 0; rr < 4; ++rr){
          lsU[pi][lane][(f * 4 + rr) * 2 + 0] = acc[f][0][rr];
          lsU[pi][lane][(f * 4 + rr) * 2 + 1] = acc[f][1][rr];
        }
    }
    __syncthreads();
    if (mat == 0){
      #pragma unroll
      for (int f = 0; f < 3; ++f)
        #pragma unroll
        for (int rr = 0; rr < 4; ++rr){
          int r = r0 + f * 16 + 4 * q + rr;
          if (r < n_e){
            int slot = beg + r;
            float wgt = list_w[slot];
            float g0 = acc[f][0][rr], g1 = acc[f][1][rr];
            float u0 = lsU[pi][lane][(f * 4 + rr) * 2 + 0];
            float u1 = lsU[pi][lane][(f * 4 + rr) * 2 + 1];
            float h0 = (g0 / (1.f + expf(-g0))) * u0 * wgt;
            float h1 = (g1 / (1.f + expf(-g1))) * u1 * wgt;
            unsigned pk = (unsigned)f2bf(h0) | ((unsigned)f2bf(h1) << 16);
            *(unsigned*)(act + (size_t)slot * INTER + iw + 2 * cL) = pk;
          }
        }
    }
    __syncthreads();    // protect lsU reuse on the (rare) extra r0 pass
  }
}

// ---------------- kernel 6: down-proj GEMM ----------------
// Same wave-autonomous structure, single matrix, fully barrier-free.
// Block = 48 rows x 128 cols (4 waves x 32); KT = 24.
__global__ __launch_bounds__(256) void k_down(
    const unsigned short* __restrict__ act, const float* __restrict__ wd,
    const int* __restrict__ offs, const int* __restrict__ list_t,
    float* __restrict__ contrib, float* __restrict__ out, int atomicMode){
  int bid = blockIdx.x;                 // 4096 = 1024 pairs x 4 grps
  int xcd = bid & 7, seq = bid >> 3;    // seq 0..511
  int pair = (seq >> 2) * 8 + xcd;      // 0..1023
  int grp  = seq & 3;
  int e = pair >> 4, ib = pair & 15;
  int beg = offs[e], n_e = offs[e + 1] - beg;
  int tid = threadIdx.x, lane = tid & 63, w = tid >> 6;
  int cL = lane & 15, q = lane >> 4;
  int nw = ib * 128 + w * 32;

  const float* bP = wd + (size_t)e * INTER * HID + (size_t)(8 * q) * HID + nw + 2 * cL;

#define DN_LA(T, A_) { _Pragma("unroll") for (int f = 0; f < 3; ++f) \
      A_[f] = *(const short8*)(aP[f] + (T) * 32); }
#define DN_LB(T, B_) { _Pragma("unroll") for (int j = 0; j < 8; ++j) \
      B_[j] = *(const float2*)(bP + (size_t)((T) * 32 + j) * HID); }
#define DN_CP(A_, B_) { \
      union { unsigned u[4]; short8 s; } f0, f1; \
      _Pragma("unroll") for (int rI = 0; rI < 4; ++rI){ \
        f0.u[rI] = cvtpk(B_[2*rI].x, B_[2*rI+1].x); \
        f1.u[rI] = cvtpk(B_[2*rI].y, B_[2*rI+1].y); } \
      _Pragma("unroll") for (int f = 0; f < 3; ++f){ \
        acc[f][0] = __builtin_amdgcn_mfma_f32_16x16x32_bf16(A_[f], f0.s, acc[f][0], 0, 0, 0); \
        acc[f][1] = __builtin_amdgcn_mfma_f32_16x16x32_bf16(A_[f], f1.s, acc[f][1], 0, 0, 0); } }

  for (int r0 = grp * 48; r0 < n_e; r0 += 192){
    const unsigned short* aP[3];
    int slotF[3];
    #pragma unroll
    for (int f = 0; f < 3; ++f){
      int r = r0 + f * 16 + cL;
      slotF[f] = (r < n_e) ? (beg + r) : beg;
      aP[f] = act + (size_t)slotF[f] * INTER + 8 * q;
    }
    short8 a0[3], a1[3];
    float2 b0[8], b1[8];
    f32x4 acc[3][2] = {};

    DN_LA(0, a0); DN_LB(0, b0);
    #pragma unroll 1
    for (int t = 0; t < 24; t += 2){
      DN_LA(t + 1, a1); DN_LB(t + 1, b1);
      DN_CP(a0, b0);
      if (t + 2 < 24){ DN_LA(t + 2, a0); DN_LB(t + 2, b0); }
      DN_CP(a1, b1);
    }

    #pragma unroll
    for (int f = 0; f < 3; ++f)
      #pragma unroll
      for (int rr = 0; rr < 4; ++rr){
        int r = r0 + f * 16 + 4 * q + rr;
        if (r < n_e){
          int slot = beg + r;
          int h = nw + 2 * cL;
          float v0 = acc[f][0][rr], v1 = acc[f][1][rr];
          if (atomicMode){
            int tok = list_t[slot];
            atomicAdd(&out[(size_t)tok * HID + h],     v0);
            atomicAdd(&out[(size_t)tok * HID + h + 1], v1);
          } else {
            float2 st; st.x = v0; st.y = v1;
            *(float2*)(contrib + (size_t)slot * HID + h) = st;
          }
        }
      }
  }
}

// ---------------- kernel 7: deterministic 8-way combine ----------------
__global__ void k_reduce(const float* __restrict__ contrib, const int* __restrict__ slot_of,
                         float* __restrict__ out){
  int bx = blockIdx.x;
  int t = bx >> 1, seg = bx & 1, tid = threadIdx.x;
  __shared__ int ss[TOPK];
  if (tid < TOPK) ss[tid] = slot_of[t * TOPK + tid];
  __syncthreads();
  int h = (seg * 256 + tid) * 4;
  f32x4 s = {0.f, 0.f, 0.f, 0.f};
  #pragma unroll
  for (int k = 0; k < TOPK; ++k){
    f32x4 v = *(const f32x4*)(contrib + (size_t)ss[k] * HID + h);
    s += v;
  }
  *(f32x4*)(out + (size_t)t * HID + h) = s;
}

extern "C" void kernel_launch(void* const* d_in, const int* in_sizes, int n_in,
                              void* d_out, int out_size, void* d_ws, size_t ws_size,
                              hipStream_t stream){
  const float* x   = (const float*)d_in[0];
  const float* gw  = (const float*)d_in[1];
  const float* wgp = (const float*)d_in[2];
  const float* wup = (const float*)d_in[3];
  const float* wdp = (const float*)d_in[4];
  float* out = (float*)d_out;
  char* ws = (char*)d_ws;

  int*   top_idx = (int*)  (ws + 0);
  float* top_w   = (float*)(ws + 32768);
  int*   offs    = (int*)  (ws + 65536);
  int*   list_t  = (int*)  (ws + 69632);
  float* list_w  = (float*)(ws + 102400);
  int*   slot_of = (int*)  (ws + 135168);
  unsigned short* xbf = (unsigned short*)(ws + 167936);             // 4 MB
  unsigned short* act = (unsigned short*)(ws + 167936 + 4194304);   // 12 MB
  float* contrib = (float*)(ws + 167936 + 4194304 + 12582912);      // 64 MB
  size_t need_full = (size_t)167936 + 4194304 + 12582912 + 67108864;
  int atomicMode = (ws_size < need_full) ? 1 : 0;

  k_convert_x<<<1024, 256, 0, stream>>>(x, xbf);
  k_router   <<<1024, 256, 0, stream>>>(x, gw, top_idx, top_w);
  k_hist     <<<1,    256, 0, stream>>>(top_idx, offs);
  k_compact  <<<64,   256, 0, stream>>>(top_idx, top_w, offs, list_t, list_w, slot_of);
  k_gateup   <<<3072, 256, 0, stream>>>(xbf, wgp, wup, offs, list_t, list_w, act);
  if (atomicMode){
    hipMemsetAsync(d_out, 0, (size_t)out_size * sizeof(float), stream);
    k_down  <<<4096, 256, 0, stream>>>(act, wdp, offs, list_t, contrib, out, 1);
  } else {
    k_down  <<<4096, 256, 0, stream>>>(act, wdp, offs, list_t, contrib, out, 0);
    k_reduce<<<2048, 256, 0, stream>>>(contrib, slot_of, out);
  }
}